// Round 23
// baseline (161.542 us; speedup 1.0000x reference)
//
#include <hip/hip_runtime.h>
#include <hip/hip_fp16.h>

#define MAXD 192
#define NCH  16

#define RFL_I(x) __builtin_amdgcn_readfirstlane(x)
#define RFL_F(x) __int_as_float(__builtin_amdgcn_readfirstlane(__float_as_int(x)))
#define RDLU(v,k) ((unsigned)__builtin_amdgcn_readlane((int)(v), (k)))
#define H2(u) __builtin_bit_cast(__half2, (unsigned)(u))
#define U32(h) __builtin_bit_cast(unsigned, (h))
#define BPERM(idx, v) __int_as_float(__builtin_amdgcn_ds_bpermute((idx), __float_as_int(v)))

struct F2 { float x, y; };   // dword-aligned global pair load
#define LOADF2(base, boff) (*(const F2*)((base) + (boff)))

// One block per (level j = blockIdx.x, point n = blockIdx.y) — XCD = j.
// Waves 0-2: pass-1 (scale 1) disparity chunks; wave 3: pass-0 (scale 4).
// R23 (on R20): LOOP ROTATION — taps run BEFORE staging, on the strip
// written LAST iteration (per-wave DS is in-order: tap ds_reads issued
// before this iteration's ds_writes return old data). Removes the
// write->drain->read lgkm wait from the critical path and overlaps tap
// VALU with the just-issued front-load VMEM latency. Carry = lpkPrev
// (1 reg). Loop runs one extra clamped iteration (re-stages ch 14 with
// identical values — harmless) so there is a single code copy.
// R18-R20 recap: VMEM-instr-minimal staging (row rotation, bpermute
// cleanup + left window, 6-stride tap layout), folded bilinear weights,
// front-loaded independent loads, strip unroll 2, b32 half2 strip.
// LESSON: no big register arrays / no channel-loop unrolling (spills);
// WRITE_SIZE is the spill tripwire (~49 MB).
__global__ __launch_bounds__(256, 8) void pbm_kernel(
    const float* __restrict__ lfeat,   // (16,1,16,H,W)
    const float* __restrict__ rfeat,
    const float* __restrict__ points,  // (1,N,2)
    const int* __restrict__ pW, const int* __restrict__ pH,
    float* __restrict__ out)           // (1,N,192,8)
{
    const int W = RFL_I(*pW), H = RFL_I(*pH);
    const int HW = W * H;
    const int j   = blockIdx.x;        // XCD = j
    const int n   = blockIdx.y;
    const int tid = threadIdx.x;
    const int wv  = tid >> 6;
    const int l   = tid & 63;

    const float pxr = points[2 * n];
    const float pyr = points[2 * n + 1];
    const float pxf = floorf(pxr), pyf = floorf(pyr);
    const float fx  = RFL_F(pxr - pxf);
    const float fy  = RFL_F(pyr - pyf);
    const int   x0i = RFL_I((int)pxf);
    const int   y0i = RFL_I((int)pyf);

    __shared__ unsigned svh[4][5][68]; // per-wave right strip, half2 (2 ch packed)
    __shared__ float    val4[48];

    const bool isP0   = (wv == 3);
    const int  s_     = RFL_I(isP0 ? 4 : 1);
    const int  lvl    = RFL_I(isP0 ? j + 8 : j);
    const int  off    = RFL_I(isP0 ? 49 : wv * 64 + 65);
    const int  DC     = RFL_I(isP0 ? 48 : 64);

    // ---- strip column constants (col == lane): pair offset + folded weights
    const int   cx    = x0i + s_ * (l - off);
    const int   pairB = min(max(cx, 0), W - 2) * 4;
    const float ax0   = (((unsigned)cx       < (unsigned)W) ? 1.0f : 0.0f) * (1.0f - fx);
    const float ax1   = (((unsigned)(cx + 1) < (unsigned)W) ? 1.0f : 0.0f) * fx;
    const float w0    = ((cx >= W - 1) ? 0.f : ax0) + ((cx >= 0) ? 0.f : ax1);
    const float w1    = ((cx >= W - 1) ? ax0 : 0.f) + ((cx >= 0) ? ax1 : 0.f);

    // ---- cleanup (pass-1): lanes 0-23 = (raw row min(l>>2,5)) x (col l&3) ----
    const int   dcx  = x0i + (64 + (l & 3)) - off;          // s=1 only
    const float dax0 = (((unsigned)dcx       < (unsigned)W) ? 1.0f : 0.0f) * (1.0f - fx);
    const float dax1 = (((unsigned)(dcx + 1) < (unsigned)W) ? 1.0f : 0.0f) * fx;
    const float w0d  = ((dcx >= W - 1) ? 0.f : dax0) + ((dcx >= 0) ? 0.f : dax1);
    const float w1d  = ((dcx >= W - 1) ? dax0 : 0.f) + ((dcx >= 0) ? dax1 : 0.f);
    const int   voS  = min(max(y0i + min(l >> 2, 5) - 2, 0), H - 1) * (W * 4)
                     + min(max(dcx, 0), W - 2) * 4;
    const int   dyr  = y0i + min(l >> 2, 4) - 2;            // dest-row weights
    const float dwy0 = ((unsigned)dyr       < (unsigned)H) ? (1.0f - fy) : 0.0f;
    const float dwy1 = ((unsigned)(dyr + 1) < (unsigned)H) ? fy : 0.0f;

    // ---- left window, 6-stride layout: dest tap lane = rd*6+cd ----
    const int   lq = min(l, 35);
    const int   rd = lq / 6;
    const int   cd = lq - rd * 6;
    int lrow, lcx;
    if (isP0) {                       // load-lane mapping (wave-uniform branch)
        int ls = min(l, 59);
        int ri = ls / 6, cc = ls - ri * 6;
        lrow = y0i + 4 * ((ri >> 1) - 2) + (ri & 1);        // 10 raw rows
        lcx  = x0i + 4 * (min(cc, 4) - 2);                  // clamp col: fetch-neutral
    } else {
        lrow = y0i + rd - 2;                                // 6 raw rows
        lcx  = x0i + cd - 2;
    }
    const int   loS  = min(max(lrow, 0), H - 1) * (W * 4) + min(max(lcx, 0), W - 2) * 4;
    const float gx0  = (((unsigned)lcx       < (unsigned)W) ? 1.0f : 0.0f) * (1.0f - fx);
    const float gx1  = (((unsigned)(lcx + 1) < (unsigned)W) ? 1.0f : 0.0f) * fx;
    const float lv0  = ((lcx >= W - 1) ? 0.f : gx0) + ((lcx >= 0) ? 0.f : gx1);
    const float lv1  = ((lcx >= W - 1) ? gx0 : 0.f) + ((lcx >= 0) ? gx1 : 0.f);
    const int   ib0  = isP0 ? (12 * rd + cd) * 4 : (l * 4);
    const int   ib1  = isP0 ? ((12 * rd + cd) * 4 + 24) : ((l + 6) * 4);
    const int   lyd  = y0i + s_ * (rd - 2);
    const float lwy0 = ((unsigned)lyd       < (unsigned)H) ? (1.0f - fy) : 0.0f;
    const float lwy1 = ((unsigned)(lyd + 1) < (unsigned)H) ? fy : 0.0f;

    const char* RbC = (const char*)(rfeat + (size_t)(lvl * NCH) * HW);
    const char* LbC = (const char*)(lfeat + (size_t)(lvl * NCH) * HW);

    float acc = 0.0f;
    unsigned lpkPrev = 0;
#pragma unroll 1
    for (int c = 0; c <= NCH; c += 2) {
        const int cs = (c < NCH) ? c : (NCH - 2);   // last iter: clamped re-stage
        const char* RpC0 = RbC + (size_t)cs * HW * 4;
        const char* RpC1 = RpC0 + (size_t)HW * 4;
        const char* LpC0 = LbC + (size_t)cs * HW * 4;
        const char* LpC1 = LpC0 + (size_t)HW * 4;

        // ---- FRONT-LOADED independent loads (latency hides under taps) ----
        F2 e0 = LOADF2(RpC0, voS);      // cleanup row (pass-1 meaningful)
        F2 e1 = LOADF2(RpC1, voS);
        F2 p0 = LOADF2(LpC0, loS);      // left-window row
        F2 p1 = LOADF2(LpC1, loS);

        // ---- TAPS for iteration c-2 (strip written LAST iteration;
        //      ds_reads issue before this iteration's ds_writes -> no wait
        //      on a fresh write drain; per-wave DS in-order = correctness).
        if (c >= 2 && l < DC) {
            __half2 aE = __floats2half2_rn(0.f, 0.f);
            __half2 aO = __floats2half2_rn(0.f, 0.f);
#define TAPROW(YY) {                                                        \
            const unsigned* rp = &svh[wv][YY][DC - 1 - l];                  \
            unsigned q0 = rp[0], q1 = rp[1], q2 = rp[2], q3 = rp[3], q4 = rp[4];\
            unsigned s0 = RDLU(lpkPrev, (YY)*6+0);                          \
            unsigned s1 = RDLU(lpkPrev, (YY)*6+1);                          \
            unsigned s2 = RDLU(lpkPrev, (YY)*6+2);                          \
            unsigned s3 = RDLU(lpkPrev, (YY)*6+3);                          \
            unsigned s4 = RDLU(lpkPrev, (YY)*6+4);                          \
            aE = __hadd2(aE, __habs2(__hsub2(H2(s0), H2(q0))));             \
            aO = __hadd2(aO, __habs2(__hsub2(H2(s1), H2(q1))));             \
            aE = __hadd2(aE, __habs2(__hsub2(H2(s2), H2(q2))));             \
            aO = __hadd2(aO, __habs2(__hsub2(H2(s3), H2(q3))));             \
            aE = __hadd2(aE, __habs2(__hsub2(H2(s4), H2(q4)))); }
            TAPROW(0)
            TAPROW(1)
            TAPROW(2)
            TAPROW(3)
            TAPROW(4)
#undef TAPROW
            __half2 at = __hadd2(aE, aO);
            acc += __half2float(__low2half(at)) + __half2float(__high2half(at));
        }

        // ---- STAGE iteration c (writes land after the taps' reads) ----
        if (!isP0) {
            // pass-1 strip: y-row rotation (6 row-loads), unroll 2
            int rbp = min(max(y0i - 2, 0), H - 1) * (W * 4);
            F2 a0 = LOADF2(RpC0 + rbp, pairB);
            F2 a1 = LOADF2(RpC1 + rbp, pairB);
            float h0p = fmaf(w0, a0.x, w1 * a0.y);
            float h1p = fmaf(w0, a1.x, w1 * a1.y);
#pragma unroll 2
            for (int yy = 0; yy < 5; ++yy) {
                int   yrc = y0i + yy - 1;
                int   rbc = min(max(yrc, 0), H - 1) * (W * 4);
                F2 c0 = LOADF2(RpC0 + rbc, pairB);
                F2 c1 = LOADF2(RpC1 + rbc, pairB);
                float h0c = fmaf(w0, c0.x, w1 * c0.y);
                float h1c = fmaf(w0, c1.x, w1 * c1.y);
                int   yr  = y0i + yy - 2;
                float wy0 = ((unsigned)yr  < (unsigned)H) ? (1.0f - fy) : 0.0f;
                float wy1 = ((unsigned)yrc < (unsigned)H) ? fy : 0.0f;
                svh[wv][yy][l] = U32(__floats2half2_rn(fmaf(wy0, h0p, wy1 * h0c),
                                                       fmaf(wy0, h1p, wy1 * h1c)));
                h0p = h0c; h1p = h1c;
            }
            // cleanup rotation: lerp + bpermute(+4) on front-loaded e
            {
                float g0 = fmaf(w0d, e0.x, w1d * e0.y);
                float g1 = fmaf(w0d, e1.x, w1d * e1.y);
                float g0n = BPERM((l + 4) * 4, g0);
                float g1n = BPERM((l + 4) * 4, g1);
                if (l < 20)
                    svh[wv][l >> 2][64 + (l & 3)] =
                        U32(__floats2half2_rn(fmaf(dwy0, g0, dwy1 * g0n),
                                              fmaf(dwy0, g1, dwy1 * g1n)));
            }
        } else if (l < 52) {
            // pass-0 strip: s=4, rows disjoint -> classic rows, unroll 2
#pragma unroll 2
            for (int yy = 0; yy < 5; ++yy) {
                int   yr   = y0i + 4 * (yy - 2);
                int   rbB0 = min(max(yr, 0), H - 1) * (W * 4);
                int   rbB1 = min(max(yr + 1, 0), H - 1) * (W * 4);
                float wy0  = ((unsigned)yr       < (unsigned)H) ? (1.0f - fy) : 0.0f;
                float wy1  = ((unsigned)(yr + 1) < (unsigned)H) ? fy : 0.0f;
                F2 a0 = LOADF2(RpC0 + rbB0, pairB);
                F2 b0 = LOADF2(RpC0 + rbB1, pairB);
                F2 a1 = LOADF2(RpC1 + rbB0, pairB);
                F2 b1 = LOADF2(RpC1 + rbB1, pairB);
                float h00 = fmaf(w0, a0.x, w1 * a0.y);
                float h01 = fmaf(w0, b0.x, w1 * b0.y);
                float h10 = fmaf(w0, a1.x, w1 * a1.y);
                float h11 = fmaf(w0, b1.x, w1 * b1.y);
                svh[wv][yy][l] = U32(__floats2half2_rn(fmaf(wy0, h00, wy1 * h01),
                                                       fmaf(wy0, h10, wy1 * h11)));
            }
        }

        // left window: lerp + 2 bpermutes on front-loaded p
        {
            float h0 = fmaf(lv0, p0.x, lv1 * p0.y);
            float h1 = fmaf(lv0, p1.x, lv1 * p1.y);
            float a0 = BPERM(ib0, h0), b0 = BPERM(ib1, h0);
            float a1 = BPERM(ib0, h1), b1 = BPERM(ib1, h1);
            lpkPrev = U32(__floats2half2_rn(fmaf(lwy0, a0, lwy1 * b0),
                                            fmaf(lwy0, a1, lwy1 * b1)));
        }
    }

    if (isP0 && l < 48)
        val4[l] = 1.0f - expf(-acc * (1.0f / 400.0f));

    __syncthreads();                     // the ONLY block-wide barrier

    if (tid < MAXD) {                    // waves 0-2: d == tid
        float v1  = 1.0f - expf(-acc * (1.0f / 400.0f));
        float pos = (float)tid * (47.0f / 191.0f);
        float i0f = floorf(pos);
        int   i0  = (int)i0f;
        float w   = pos - i0f;
        int   i1  = min(i0 + 1, 47);
        float up  = val4[i0] + w * (val4[i1] - val4[i0]);
        out[((size_t)n * MAXD + tid) * 8 + j] = v1 + up;
    }
}

extern "C" void kernel_launch(void* const* d_in, const int* in_sizes, int n_in,
                              void* d_out, int out_size, void* d_ws, size_t ws_size,
                              hipStream_t stream) {
    const float* lf  = (const float*)d_in[0];
    const float* rf  = (const float*)d_in[1];
    const float* pts = (const float*)d_in[2];
    const int*   pW  = (const int*)d_in[3];
    const int*   pH  = (const int*)d_in[4];
    float* out = (float*)d_out;

    const int N = in_sizes[2] / 2;       // (B=1, N, 2)
    pbm_kernel<<<dim3(8, N), 256, 0, stream>>>(lf, rf, pts, pW, pH, out);
}

// Round 24
// 144.812 us; speedup vs baseline: 1.1155x; 1.1155x over previous
//
#include <hip/hip_runtime.h>
#include <hip/hip_fp16.h>

#define MAXD 192
#define NCH  16

#define RFL_I(x) __builtin_amdgcn_readfirstlane(x)
#define RFL_F(x) __int_as_float(__builtin_amdgcn_readfirstlane(__float_as_int(x)))
#define RDLU(v,k) ((unsigned)__builtin_amdgcn_readlane((int)(v), (k)))
#define H2(u) __builtin_bit_cast(__half2, (unsigned)(u))
#define U32(h) __builtin_bit_cast(unsigned, (h))
#define BPERM(idx, v) __int_as_float(__builtin_amdgcn_ds_bpermute((idx), __float_as_int(v)))

struct F2 { float x, y; };   // align 4: dword-aligned global pair load
#define LOADF2(base, boff) (*(const F2*)((base) + (boff)))

// ===== R24 == R20 verbatim (measured best: 145.2 µs) =====
// One block per (level j = blockIdx.x, point n = blockIdx.y) — XCD = j.
// Waves 0-2: pass-1 (scale 1) disparity chunks; wave 3: pass-0 (scale 4).
// Techniques (each verified by counter deltas):
//  - VMEM-instr-minimal staging: y-row rotation (1 load/raw row/channel),
//    bpermute-based cleanup + left window, 6-stride tap layout (R18/R19).
//  - dwordx2 pair-loads with clamp-select + x-validity folded into two
//    loop-invariant weights (R10).
//  - front-loaded independent loads + strip unroll 2 for ILP (R20).
//  - packed half2 strip / pk-f16 taps (R12), readlane broadcast (R7).
//  - grid (8,N): XCD=j, per-XCD read set = 1 level pair ~7.9 MB (R15).
// CLOSED dead-ends: register pipelining/batching spills (R5/6/8/9/14/16/
// R21); DS-cut flat (R22); loop rotation zero + extra-iter cost (R23);
// VALU-cut flat (R12); wave-split flat (R17).
__global__ __launch_bounds__(256, 8) void pbm_kernel(
    const float* __restrict__ lfeat,   // (16,1,16,H,W)
    const float* __restrict__ rfeat,
    const float* __restrict__ points,  // (1,N,2)
    const int* __restrict__ pW, const int* __restrict__ pH,
    float* __restrict__ out)           // (1,N,192,8)
{
    const int W = RFL_I(*pW), H = RFL_I(*pH);
    const int HW = W * H;
    const int j   = blockIdx.x;        // XCD = j
    const int n   = blockIdx.y;
    const int tid = threadIdx.x;
    const int wv  = tid >> 6;
    const int l   = tid & 63;

    const float pxr = points[2 * n];
    const float pyr = points[2 * n + 1];
    const float pxf = floorf(pxr), pyf = floorf(pyr);
    const float fx  = RFL_F(pxr - pxf);
    const float fy  = RFL_F(pyr - pyf);
    const int   x0i = RFL_I((int)pxf);
    const int   y0i = RFL_I((int)pyf);

    __shared__ unsigned svh[4][5][68]; // per-wave right strip, half2 (2 ch packed)
    __shared__ float    val4[48];

    const bool isP0   = (wv == 3);
    const int  s_     = RFL_I(isP0 ? 4 : 1);
    const int  lvl    = RFL_I(isP0 ? j + 8 : j);
    const int  off    = RFL_I(isP0 ? 49 : wv * 64 + 65);
    const int  DC     = RFL_I(isP0 ? 48 : 64);

    // ---- strip column constants (col == lane): pair offset + folded weights
    const int   cx    = x0i + s_ * (l - off);
    const int   pairB = min(max(cx, 0), W - 2) * 4;
    const float ax0   = (((unsigned)cx       < (unsigned)W) ? 1.0f : 0.0f) * (1.0f - fx);
    const float ax1   = (((unsigned)(cx + 1) < (unsigned)W) ? 1.0f : 0.0f) * fx;
    const float w0    = ((cx >= W - 1) ? 0.f : ax0) + ((cx >= 0) ? 0.f : ax1);
    const float w1    = ((cx >= W - 1) ? ax0 : 0.f) + ((cx >= 0) ? ax1 : 0.f);

    // ---- cleanup (pass-1): lanes 0-23 = (raw row min(l>>2,5)) x (col l&3) ----
    const int   dcx  = x0i + (64 + (l & 3)) - off;          // s=1 only
    const float dax0 = (((unsigned)dcx       < (unsigned)W) ? 1.0f : 0.0f) * (1.0f - fx);
    const float dax1 = (((unsigned)(dcx + 1) < (unsigned)W) ? 1.0f : 0.0f) * fx;
    const float w0d  = ((dcx >= W - 1) ? 0.f : dax0) + ((dcx >= 0) ? 0.f : dax1);
    const float w1d  = ((dcx >= W - 1) ? dax0 : 0.f) + ((dcx >= 0) ? dax1 : 0.f);
    const int   voS  = min(max(y0i + min(l >> 2, 5) - 2, 0), H - 1) * (W * 4)
                     + min(max(dcx, 0), W - 2) * 4;
    const int   dyr  = y0i + min(l >> 2, 4) - 2;            // dest-row weights
    const float dwy0 = ((unsigned)dyr       < (unsigned)H) ? (1.0f - fy) : 0.0f;
    const float dwy1 = ((unsigned)(dyr + 1) < (unsigned)H) ? fy : 0.0f;

    // ---- left window, 6-stride layout: dest tap lane = rd*6+cd ----
    const int   lq = min(l, 35);
    const int   rd = lq / 6;
    const int   cd = lq - rd * 6;
    int lrow, lcx;
    if (isP0) {                       // load-lane mapping (wave-uniform branch)
        int ls = min(l, 59);
        int ri = ls / 6, cc = ls - ri * 6;
        lrow = y0i + 4 * ((ri >> 1) - 2) + (ri & 1);        // 10 raw rows
        lcx  = x0i + 4 * (min(cc, 4) - 2);                  // clamp col: fetch-neutral
    } else {
        lrow = y0i + rd - 2;                                // 6 raw rows
        lcx  = x0i + cd - 2;
    }
    const int   loS  = min(max(lrow, 0), H - 1) * (W * 4) + min(max(lcx, 0), W - 2) * 4;
    const float gx0  = (((unsigned)lcx       < (unsigned)W) ? 1.0f : 0.0f) * (1.0f - fx);
    const float gx1  = (((unsigned)(lcx + 1) < (unsigned)W) ? 1.0f : 0.0f) * fx;
    const float lv0  = ((lcx >= W - 1) ? 0.f : gx0) + ((lcx >= 0) ? 0.f : gx1);
    const float lv1  = ((lcx >= W - 1) ? gx0 : 0.f) + ((lcx >= 0) ? gx1 : 0.f);
    const int   ib0  = isP0 ? (12 * rd + cd) * 4 : (l * 4);
    const int   ib1  = isP0 ? ((12 * rd + cd) * 4 + 24) : ((l + 6) * 4);
    const int   lyd  = y0i + s_ * (rd - 2);
    const float lwy0 = ((unsigned)lyd       < (unsigned)H) ? (1.0f - fy) : 0.0f;
    const float lwy1 = ((unsigned)(lyd + 1) < (unsigned)H) ? fy : 0.0f;

    const char* RbC = (const char*)(rfeat + (size_t)(lvl * NCH) * HW);
    const char* LbC = (const char*)(lfeat + (size_t)(lvl * NCH) * HW);

    float acc = 0.0f;
#pragma unroll 1
    for (int c = 0; c < NCH; c += 2) {
        const char* RpC0 = RbC + (size_t)c * HW * 4;
        const char* RpC1 = RpC0 + (size_t)HW * 4;
        const char* LpC0 = LbC + (size_t)c * HW * 4;
        const char* LpC1 = LpC0 + (size_t)HW * 4;

        // ---- FRONT-LOADED independent loads (latency hides under strip) ----
        F2 e0 = LOADF2(RpC0, voS);      // cleanup row (pass-1 meaningful)
        F2 e1 = LOADF2(RpC1, voS);
        F2 p0 = LOADF2(LpC0, loS);      // left-window row
        F2 p1 = LOADF2(LpC1, loS);

        if (!isP0) {
            // ---- pass-1 strip: y-row rotation (6 row-loads), unroll 2 ----
            int rbp = min(max(y0i - 2, 0), H - 1) * (W * 4);
            F2 a0 = LOADF2(RpC0 + rbp, pairB);
            F2 a1 = LOADF2(RpC1 + rbp, pairB);
            float h0p = fmaf(w0, a0.x, w1 * a0.y);
            float h1p = fmaf(w0, a1.x, w1 * a1.y);
#pragma unroll 2
            for (int yy = 0; yy < 5; ++yy) {
                int   yrc = y0i + yy - 1;
                int   rbc = min(max(yrc, 0), H - 1) * (W * 4);
                F2 c0 = LOADF2(RpC0 + rbc, pairB);
                F2 c1 = LOADF2(RpC1 + rbc, pairB);
                float h0c = fmaf(w0, c0.x, w1 * c0.y);
                float h1c = fmaf(w0, c1.x, w1 * c1.y);
                int   yr  = y0i + yy - 2;
                float wy0 = ((unsigned)yr  < (unsigned)H) ? (1.0f - fy) : 0.0f;
                float wy1 = ((unsigned)yrc < (unsigned)H) ? fy : 0.0f;
                svh[wv][yy][l] = U32(__floats2half2_rn(fmaf(wy0, h0p, wy1 * h0c),
                                                       fmaf(wy0, h1p, wy1 * h1c)));
                h0p = h0c; h1p = h1c;
            }
            // ---- cleanup rotation: lerp + bpermute(+4) on front-loaded e ----
            {
                float g0 = fmaf(w0d, e0.x, w1d * e0.y);
                float g1 = fmaf(w0d, e1.x, w1d * e1.y);
                float g0n = BPERM((l + 4) * 4, g0);
                float g1n = BPERM((l + 4) * 4, g1);
                if (l < 20)
                    svh[wv][l >> 2][64 + (l & 3)] =
                        U32(__floats2half2_rn(fmaf(dwy0, g0, dwy1 * g0n),
                                              fmaf(dwy0, g1, dwy1 * g1n)));
            }
        } else if (l < 52) {
            // ---- pass-0 strip: s=4, rows disjoint -> classic rows, unroll 2 ----
#pragma unroll 2
            for (int yy = 0; yy < 5; ++yy) {
                int   yr   = y0i + 4 * (yy - 2);
                int   rbB0 = min(max(yr, 0), H - 1) * (W * 4);
                int   rbB1 = min(max(yr + 1, 0), H - 1) * (W * 4);
                float wy0  = ((unsigned)yr       < (unsigned)H) ? (1.0f - fy) : 0.0f;
                float wy1  = ((unsigned)(yr + 1) < (unsigned)H) ? fy : 0.0f;
                F2 a0 = LOADF2(RpC0 + rbB0, pairB);
                F2 b0 = LOADF2(RpC0 + rbB1, pairB);
                F2 a1 = LOADF2(RpC1 + rbB0, pairB);
                F2 b1 = LOADF2(RpC1 + rbB1, pairB);
                float h00 = fmaf(w0, a0.x, w1 * a0.y);
                float h01 = fmaf(w0, b0.x, w1 * b0.y);
                float h10 = fmaf(w0, a1.x, w1 * a1.y);
                float h11 = fmaf(w0, b1.x, w1 * b1.y);
                svh[wv][yy][l] = U32(__floats2half2_rn(fmaf(wy0, h00, wy1 * h01),
                                                       fmaf(wy0, h10, wy1 * h11)));
            }
        }

        // ---- left window: lerp + 2 bpermutes on front-loaded p ----
        unsigned lpk;
        {
            float h0 = fmaf(lv0, p0.x, lv1 * p0.y);
            float h1 = fmaf(lv0, p1.x, lv1 * p1.y);
            float a0 = BPERM(ib0, h0), b0 = BPERM(ib1, h0);
            float a1 = BPERM(ib0, h1), b1 = BPERM(ib1, h1);
            lpk = U32(__floats2half2_rn(fmaf(lwy0, a0, lwy1 * b0),
                                        fmaf(lwy0, a1, lwy1 * b1)));
        }

        if (l < DC) {
            __half2 aE = __floats2half2_rn(0.f, 0.f);
            __half2 aO = __floats2half2_rn(0.f, 0.f);
#define TAPROW(YY) {                                                        \
            const unsigned* rp = &svh[wv][YY][DC - 1 - l];                  \
            unsigned q0 = rp[0], q1 = rp[1], q2 = rp[2], q3 = rp[3], q4 = rp[4];\
            unsigned s0 = RDLU(lpk, (YY)*6+0);                              \
            unsigned s1 = RDLU(lpk, (YY)*6+1);                              \
            unsigned s2 = RDLU(lpk, (YY)*6+2);                              \
            unsigned s3 = RDLU(lpk, (YY)*6+3);                              \
            unsigned s4 = RDLU(lpk, (YY)*6+4);                              \
            aE = __hadd2(aE, __habs2(__hsub2(H2(s0), H2(q0))));             \
            aO = __hadd2(aO, __habs2(__hsub2(H2(s1), H2(q1))));             \
            aE = __hadd2(aE, __habs2(__hsub2(H2(s2), H2(q2))));             \
            aO = __hadd2(aO, __habs2(__hsub2(H2(s3), H2(q3))));             \
            aE = __hadd2(aE, __habs2(__hsub2(H2(s4), H2(q4)))); }
            TAPROW(0)
            TAPROW(1)
            TAPROW(2)
            TAPROW(3)
            TAPROW(4)
#undef TAPROW
            __half2 at = __hadd2(aE, aO);
            acc += __half2float(__low2half(at)) + __half2float(__high2half(at));
        }
    }

    if (isP0 && l < 48)
        val4[l] = 1.0f - expf(-acc * (1.0f / 400.0f));

    __syncthreads();                     // the ONLY block-wide barrier

    if (tid < MAXD) {                    // waves 0-2: d == tid
        float v1  = 1.0f - expf(-acc * (1.0f / 400.0f));
        float pos = (float)tid * (47.0f / 191.0f);
        float i0f = floorf(pos);
        int   i0  = (int)i0f;
        float w   = pos - i0f;
        int   i1  = min(i0 + 1, 47);
        float up  = val4[i0] + w * (val4[i1] - val4[i0]);
        out[((size_t)n * MAXD + tid) * 8 + j] = v1 + up;
    }
}

extern "C" void kernel_launch(void* const* d_in, const int* in_sizes, int n_in,
                              void* d_out, int out_size, void* d_ws, size_t ws_size,
                              hipStream_t stream) {
    const float* lf  = (const float*)d_in[0];
    const float* rf  = (const float*)d_in[1];
    const float* pts = (const float*)d_in[2];
    const int*   pW  = (const int*)d_in[3];
    const int*   pH  = (const int*)d_in[4];
    float* out = (float*)d_out;

    const int N = in_sizes[2] / 2;       // (B=1, N, 2)
    pbm_kernel<<<dim3(8, N), 256, 0, stream>>>(lf, rf, pts, pW, pH, out);
}